// Round 5
// baseline (7771.487 us; speedup 1.0000x reference)
//
#include <hip/hip_runtime.h>

// Problem constants
#define BB 16
#define SS 2048
#define DD 256
#define ND4 1024   // 4*D
#define PRD 16     // R-buffer slot depth (residual stream)
#define PGD 8      // GX-buffer slot depth (gate pre-activations)
#define HLP 4      // helper WGs per layer

typedef __attribute__((ext_vector_type(8))) _Float16 half8;
typedef __attribute__((ext_vector_type(4))) float f32x4;
typedef unsigned long long u64;
union H8 { half8 v; unsigned int u[4]; uint4 q; };

__device__ __forceinline__ u64 aload(const u64* p) {
    return __hip_atomic_load(p, __ATOMIC_RELAXED, __HIP_MEMORY_SCOPE_AGENT);
}
__device__ __forceinline__ void astore(u64* p, u64 v) {
    __hip_atomic_store(p, v, __ATOMIC_RELAXED, __HIP_MEMORY_SCOPE_AGENT);
}
__device__ __forceinline__ unsigned pload(const unsigned* p) {
    return __hip_atomic_load(p, __ATOMIC_RELAXED, __HIP_MEMORY_SCOPE_AGENT);
}
__device__ __forceinline__ void pstore(unsigned* p, unsigned v) {
    __hip_atomic_store(p, v, __ATOMIC_RELAXED, __HIP_MEMORY_SCOPE_AGENT);
}
__device__ __forceinline__ int aflag(int* p) {
    return __hip_atomic_load(p, __ATOMIC_RELAXED, __HIP_MEMORY_SCOPE_AGENT);
}
__device__ __forceinline__ void sflag(int* p) {
    __hip_atomic_store(p, 1, __ATOMIC_RELAXED, __HIP_MEMORY_SCOPE_AGENT);
}
__device__ __forceinline__ unsigned short f16b(float x) {
    union { _Float16 h; unsigned short u; } c; c.h = (_Float16)x; return c.u;
}
__device__ __forceinline__ bool spinBail(int& guard, int* af) {
    if ((++guard & 63) == 0) {
        __builtin_amdgcn_s_sleep(1);
        if (guard > (1 << 18) || aflag(af)) { sflag(af); return true; }
    }
    return false;
}

// ---------------------------------------------------------------------------
// embed: h0 = [x | tf] @ in_W + in_b
// ---------------------------------------------------------------------------
__global__ void embed_kernel(const float* __restrict__ x, const float* __restrict__ tf,
                             const float* __restrict__ inW, const float* __restrict__ inb,
                             float* __restrict__ h) {
    int tok = blockIdx.x, d = threadIdx.x;
    float xv = x[tok];
    float acc = inb[d] + xv * inW[d];
#pragma unroll
    for (int c = 0; c < 6; ++c)
        acc = fmaf(tf[tok * 6 + c], inW[(c + 1) * DD + d], acc);
    h[(size_t)tok * DD + d] = acc;
}

// ---------------------------------------------------------------------------
// Wx -> fp16 B-fragment order
// ---------------------------------------------------------------------------
__global__ void wxprep_kernel(const float* __restrict__ Wx, unsigned short* __restrict__ Wxh) {
    int l = blockIdx.x >> 6, G = blockIdx.x & 63;
    int lane = threadIdx.x, quad = lane >> 4, mm = lane & 15;
    const float* W = Wx + (size_t)l * DD * ND4;
    unsigned short* o = Wxh + (size_t)blockIdx.x * 4096;
#pragma unroll
    for (int kc = 0; kc < 8; ++kc) {
        __align__(16) unsigned short tmp[8];
#pragma unroll
        for (int i = 0; i < 8; ++i)
            tmp[i] = f16b(W[(size_t)(kc * 32 + quad * 8 + i) * ND4 + G * 16 + mm]);
        *(uint4*)(o + ((size_t)kc * 64 + lane) * 8) = *(uint4*)tmp;
    }
}

// ---------------------------------------------------------------------------
// Mega kernel (R4 topology, R5 latency surgery):
//  - X-publish moved directly after hval (before residual/prog work)
//  - GX/R acquire early-issued, tag-verified after the Wh MFMAs
//  - prog slot-reuse gates cached (refresh only when slack exhausted)
//  - single barrier per scan step; gbuf padded [16][17] (bank conflicts)
// ---------------------------------------------------------------------------
__global__ __launch_bounds__(256, 1) void mega_kernel(
    const float* __restrict__ hemb, const float* __restrict__ Wh,
    const float* __restrict__ lng, const float* __restrict__ lnb,
    const float* __restrict__ bgp, const unsigned short* __restrict__ Wxh,
    float* __restrict__ hout,
    u64* __restrict__ Xbuf, u64* __restrict__ Rbuf, u64* __restrict__ GXbuf,
    unsigned* __restrict__ prog, int* __restrict__ abortFlag) {
    __shared__ __align__(16) char smemBlob[57344];  // forces <=2 WGs/CU
    const int bid = blockIdx.x;
    const int tid = threadIdx.x;

    if (bid < 64) {
        // ================= SCAN ROLE =================
        const int l = bid >> 4, g = bid & 15;
        const int w = tid >> 6, lane = tid & 63;
        const int mm = lane & 15, quad = lane >> 4;
        const int sb = tid >> 4, sd = tid & 15;
        const int dglob = g * 16 + sd;
        float (*gbuf)[4][16][17] = (float (*)[4][16][17])smemBlob;  // padded

        H8 bfr[8];
        {
            const float* WhL = Wh + (size_t)l * DD * ND4;
            const int col = w * 256 + g * 16 + mm;
#pragma unroll
            for (int kc = 0; kc < 8; ++kc)
#pragma unroll
                for (int p = 0; p < 4; ++p) {
                    float f0 = WhL[(size_t)(32 * kc + 8 * quad + 2 * p) * ND4 + col];
                    float f1 = WhL[(size_t)(32 * kc + 8 * quad + 2 * p + 1) * ND4 + col];
                    bfr[kc].u[p] = (unsigned)f16b(f0) | ((unsigned)f16b(f1) << 16);
                }
        }

        float c_ = 0.f, n_ = 0.f, m_ = 0.f;

        u64* Xl = Xbuf + (size_t)l * 4096;
        const u64* Rprev = Rbuf + (size_t)(l > 0 ? l - 1 : 0) * PRD * 4096;
        u64* Rcur = Rbuf + (size_t)(l < 3 ? l : 0) * PRD * 4096;
        const u64* GXl = GXbuf + (size_t)l * PGD * 16384;

        const int pquad = (dglob >> 3) & 3;
        const int ppair = (sd >> 1) & 3;
        const size_t pubIdx = (size_t)(g >> 1) * 256 + (size_t)pquad * 64 + (size_t)sb * 4 + ppair;
        const bool doPub = (sd & 1) == 0;
        const size_t rdBase = (size_t)quad * 64 + (size_t)mm * 4;
        const size_t gxIdx = (size_t)sb * 1024 + dglob;
        const size_t rIdx = (size_t)sb * 256 + dglob;
        const float* hemb0 = hemb + (size_t)sb * SS * DD + dglob;
        float* hrow = hout + (size_t)sb * SS * DD + dglob;
        const unsigned* psP = prog + (l + 1);
        const unsigned* pgP = prog + 4 + (l + 1) * 4;
        unsigned psC = 0, pgMinC = 0;   // cached downstream progress
        __syncthreads();

        for (int t = 0; t < SS; ++t) {
            const unsigned tagT = (unsigned)(t + 1);
            // ---- A. early-issue GX (+R) acquire loads ----
            const u64* Gp = GXl + (size_t)(t & (PGD - 1)) * 16384 + gxIdx;
            const u64* Rp = Rprev + (size_t)(t & (PRD - 1)) * 4096 + rIdx;
            u64 a0 = aload(Gp), a1 = aload(Gp + 256);
            u64 a2 = aload(Gp + 512), a3 = aload(Gp + 768);
            u64 ar = 0;
            if (l > 0) ar = aload(Rp);
            float hembv = (l == 0) ? hemb0[(size_t)t * DD] : 0.f;

            // ---- B. X rendezvous for h_s(t-1) ----
            f32x4 acc0 = {0.f, 0.f, 0.f, 0.f}, acc1 = {0.f, 0.f, 0.f, 0.f};
            if (t > 0) {
                const unsigned tag = (unsigned)t;
                u64* Xp = Xl + (size_t)(t & 1) * 2048;
                u64 v[32];
                int guard = 0;
                for (;;) {
#pragma unroll
                    for (int kc = 0; kc < 8; ++kc)
#pragma unroll
                        for (int p = 0; p < 4; ++p)
                            v[kc * 4 + p] = aload(Xp + (size_t)kc * 256 + rdBase + p);
                    bool ok = true;
#pragma unroll
                    for (int i = 0; i < 32; ++i) ok &= ((unsigned)(v[i] >> 32) == tag);
                    if (ok) break;
                    if ((++guard & 255) == 0) {
                        if (guard > (1 << 18) || aflag(abortFlag)) { sflag(abortFlag); break; }
                    }
                }
                H8 afr[8];
#pragma unroll
                for (int kc = 0; kc < 8; ++kc)
#pragma unroll
                    for (int p = 0; p < 4; ++p) afr[kc].u[p] = (unsigned)v[kc * 4 + p];
                acc0 = __builtin_amdgcn_mfma_f32_16x16x32_f16(afr[0].v, bfr[0].v, acc0, 0, 0, 0);
                acc1 = __builtin_amdgcn_mfma_f32_16x16x32_f16(afr[1].v, bfr[1].v, acc1, 0, 0, 0);
                acc0 = __builtin_amdgcn_mfma_f32_16x16x32_f16(afr[2].v, bfr[2].v, acc0, 0, 0, 0);
                acc1 = __builtin_amdgcn_mfma_f32_16x16x32_f16(afr[3].v, bfr[3].v, acc1, 0, 0, 0);
                acc0 = __builtin_amdgcn_mfma_f32_16x16x32_f16(afr[4].v, bfr[4].v, acc0, 0, 0, 0);
                acc1 = __builtin_amdgcn_mfma_f32_16x16x32_f16(afr[5].v, bfr[5].v, acc1, 0, 0, 0);
                acc0 = __builtin_amdgcn_mfma_f32_16x16x32_f16(afr[6].v, bfr[6].v, acc0, 0, 0, 0);
                acc1 = __builtin_amdgcn_mfma_f32_16x16x32_f16(afr[7].v, bfr[7].v, acc1, 0, 0, 0);
            }
            f32x4 acc = acc0 + acc1;

            // ---- C. verify GX/R tags (steady state: already satisfied) ----
            {
                int guard = 0;
                for (;;) {
                    bool ok = ((unsigned)(a0 >> 32) == tagT) & ((unsigned)(a1 >> 32) == tagT) &
                              ((unsigned)(a2 >> 32) == tagT) & ((unsigned)(a3 >> 32) == tagT) &
                              ((l == 0) | ((unsigned)(ar >> 32) == tagT));
                    if (ok) break;
                    if (spinBail(guard, abortFlag)) break;
                    a0 = aload(Gp); a1 = aload(Gp + 256);
                    a2 = aload(Gp + 512); a3 = aload(Gp + 768);
                    if (l > 0) ar = aload(Rp);
                }
            }
            float gxi = __uint_as_float((unsigned)a0);
            float gxf = __uint_as_float((unsigned)a1);
            float gxz = __uint_as_float((unsigned)a2);
            float gxoo = __uint_as_float((unsigned)a3);
            float hin = (l > 0) ? __uint_as_float((unsigned)ar) : hembv;

            // ---- D. gbuf exchange (single barrier per step) ----
            const int par = t & 1;
#pragma unroll
            for (int r = 0; r < 4; ++r) gbuf[par][w][quad * 4 + r][mm] = acc[r];
            __syncthreads();

            // ---- E. gates ----
            float gi = gbuf[par][0][sb][sd] + gxi;
            float gf = gbuf[par][1][sb][sd] + gxf;
            float gz = gbuf[par][2][sb][sd] + gxz;
            float go = gbuf[par][3][sb][sd] + gxoo;
            float mn = fmaxf(gf + m_, gi);
            float ip = __expf(gi - mn);
            float fp = __expf(gf + m_ - mn);
            float e2z = __expf(2.f * gz);
            float th = 1.f - 2.f * __builtin_amdgcn_rcpf(e2z + 1.f);
            c_ = fp * c_ + ip * th;
            n_ = fp * n_ + ip;
            m_ = mn;
            float sg = __builtin_amdgcn_rcpf(1.f + __expf(-go));
            float hval = sg * c_ * __builtin_amdgcn_rcpf(fmaxf(fabsf(n_), 1.f));

            // ---- F. X-publish FIRST (partners' critical path) ----
            float hodd = __shfl_down(hval, 1);
            if (doPub) {
                unsigned payload = (unsigned)f16b(hval) | ((unsigned)f16b(hodd) << 16);
                astore(Xl + (size_t)((t + 1) & 1) * 2048 + pubIdx, ((u64)tagT << 32) | payload);
            }

            // ---- G. residual out (prog gate via cache) ----
            float rnew = hin + hval;
            if (l == 3) {
                hrow[(size_t)t * DD] = rnew;
            } else {
                if (t >= PRD) {
                    unsigned needT = (unsigned)(t - PRD);
                    if (!(psC >= needT + 2 && pgMinC >= needT + 1)) {
                        int guard = 0;
                        for (;;) {
                            psC = pload(psP);
                            unsigned p0 = pload(pgP), p1 = pload(pgP + 1);
                            unsigned p2 = pload(pgP + 2), p3 = pload(pgP + 3);
                            unsigned mn01 = p0 < p1 ? p0 : p1;
                            unsigned mn23 = p2 < p3 ? p2 : p3;
                            pgMinC = mn01 < mn23 ? mn01 : mn23;
                            if (psC >= needT + 2 && pgMinC >= needT + 1) break;
                            if (spinBail(guard, abortFlag)) break;
                        }
                    }
                }
                astore(Rcur + (size_t)(t & (PRD - 1)) * 4096 + rIdx,
                       ((u64)tagT << 32) | (u64)__float_as_uint(rnew));
            }
            if (g == 0 && tid == 0) pstore(prog + l, (unsigned)(t + 1));
        }
    } else {
        // ================= HELPER ROLE: streaming gx GEMM =================
        const int hix = bid - 64;
        const int l = hix >> 2;
        const int j = hix & 3;
        const int w = tid >> 6, lane = tid & 63;
        const int mm = lane & 15, quad = lane >> 4;
        const int hb_ = tid >> 4, hd0 = (tid & 15) * 16;
        unsigned short (*hA)[264] = (unsigned short (*)[264])smemBlob;

        const u64* Rin = Rbuf + (size_t)(l > 0 ? l - 1 : 0) * PRD * 4096;
        u64* GXl = GXbuf + (size_t)l * PGD * 16384;
        const unsigned short* WxL = Wxh + (size_t)l * 262144;
        const float* lngL = lng + l * DD;
        const float* lnbL = lnb + l * DD;
        const float* bgL = bgp + (size_t)l * ND4;
        unsigned* myProg = prog + 4 + l * 4 + j;
        const unsigned* scanProg = prog + l;
        unsigned spC = 0;  // cached scan progress

        for (int t = j; t < SS; t += HLP) {
            const unsigned tagT = (unsigned)(t + 1);
            // ---- 1. acquire r[l-1][t] (or embed for l==0) ----
            float rv[16];
            if (l == 0) {
                const float4* p = (const float4*)(hemb + ((size_t)hb_ * SS + t) * DD + hd0);
#pragma unroll
                for (int q4 = 0; q4 < 4; ++q4) {
                    float4 f = p[q4];
                    rv[q4 * 4 + 0] = f.x; rv[q4 * 4 + 1] = f.y;
                    rv[q4 * 4 + 2] = f.z; rv[q4 * 4 + 3] = f.w;
                }
            } else {
                const u64* Rp = Rin + (size_t)(t & (PRD - 1)) * 4096 + (size_t)tid * 16;
                int guard = 0;
                for (;;) {
                    u64 vv[16];
#pragma unroll
                    for (int i = 0; i < 16; ++i) vv[i] = aload(Rp + i);
                    bool ok = true;
#pragma unroll
                    for (int i = 0; i < 16; ++i) ok &= ((unsigned)(vv[i] >> 32) == tagT);
                    if (ok) {
#pragma unroll
                        for (int i = 0; i < 16; ++i) rv[i] = __uint_as_float((unsigned)vv[i]);
                        break;
                    }
                    if (spinBail(guard, abortFlag)) {
#pragma unroll
                        for (int i = 0; i < 16; ++i) rv[i] = 0.f;
                        break;
                    }
                }
            }
            // ---- 2. LN stats ----
            float s = 0.f, ssq = 0.f;
#pragma unroll
            for (int i = 0; i < 16; ++i) { s += rv[i]; ssq += rv[i] * rv[i]; }
#pragma unroll
            for (int msk = 1; msk < 16; msk <<= 1) {
                s += __shfl_xor(s, msk);
                ssq += __shfl_xor(ssq, msk);
            }
            float muv = s * (1.f / 256.f);
            float rsv = rsqrtf(fmaxf(ssq * (1.f / 256.f) - muv * muv, 0.f) + 1e-5f);
            // ---- 3. LN -> fp16 -> LDS ----
            {
                __align__(16) unsigned short ov[16];
#pragma unroll
                for (int i = 0; i < 16; ++i)
                    ov[i] = f16b((rv[i] - muv) * rsv * lngL[hd0 + i] + lnbL[hd0 + i]);
                *(uint4*)&hA[hb_][hd0] = *(uint4*)&ov[0];
                *(uint4*)&hA[hb_][hd0 + 8] = *(uint4*)&ov[8];
            }
            __syncthreads();
            // ---- 4. A-frags ----
            H8 A[8];
#pragma unroll
            for (int kc = 0; kc < 8; ++kc)
                A[kc].q = *(const uint4*)&hA[mm][kc * 32 + quad * 8];
            // ---- 5. MFMA tiles ----
            f32x4 acc[16];
            const unsigned short* WxW = WxL + (size_t)w * 16 * 4096;
#pragma unroll
            for (int n = 0; n < 16; ++n) {
                const unsigned short* bp = WxW + (size_t)n * 4096 + (size_t)lane * 8;
                f32x4 a = {0.f, 0.f, 0.f, 0.f};
#pragma unroll
                for (int kc = 0; kc < 8; ++kc) {
                    H8 B;
                    B.q = *(const uint4*)(bp + (size_t)kc * 512);
                    a = __builtin_amdgcn_mfma_f32_16x16x32_f16(A[kc].v, B.v, a, 0, 0, 0);
                }
                acc[n] = a;
            }
            // ---- 6. slot-reuse gate (cached), write GX ----
            if (t >= PGD) {
                unsigned need = (unsigned)(t - PGD) + 2;
                if (spC < need) {
                    int guard = 0;
                    for (;;) {
                        spC = pload(scanProg);
                        if (spC >= need) break;
                        if (spinBail(guard, abortFlag)) break;
                    }
                }
            }
            u64* Gq = GXl + (size_t)(t & (PGD - 1)) * 16384;
#pragma unroll
            for (int n = 0; n < 16; ++n) {
                int c = (w * 16 + n) * 16 + mm;
                float bgv = bgL[c];
                f32x4 a = acc[n];
#pragma unroll
                for (int r = 0; r < 4; ++r)
                    astore(Gq + (size_t)(quad * 4 + r) * 1024 + c,
                           ((u64)tagT << 32) | (u64)__float_as_uint(a[r] + bgv));
            }
            __syncthreads();  // hA WAR for next token
            if (tid == 0) pstore(myProg, (unsigned)(t + 1));
        }
    }
}

// ---------------------------------------------------------------------------
// final: out[b] = r3[b][S-1][:] . fc_W + fc_b
// ---------------------------------------------------------------------------
__global__ void final_kernel(const float* __restrict__ h, const float* __restrict__ fcW,
                             const float* __restrict__ fcb, float* __restrict__ out) {
    int b = blockIdx.x, lane = threadIdx.x;
    const float4 hv = *(const float4*)(h + ((size_t)b * SS + (SS - 1)) * DD + lane * 4);
    const float4 wv = *(const float4*)(fcW + lane * 4);
    float s = hv.x * wv.x + hv.y * wv.y + hv.z * wv.z + hv.w * wv.w;
#pragma unroll
    for (int off = 32; off; off >>= 1) s += __shfl_down(s, off);
    if (lane == 0) out[b] = s + fcb[0];
}

// ---------------------------------------------------------------------------
extern "C" void kernel_launch(void* const* d_in, const int* in_sizes, int n_in,
                              void* d_out, int out_size, void* d_ws, size_t ws_size,
                              hipStream_t stream) {
    const float* x   = (const float*)d_in[0];
    const float* tf  = (const float*)d_in[1];
    const float* inW = (const float*)d_in[2];
    const float* inb = (const float*)d_in[3];
    const float* lng = (const float*)d_in[4];
    const float* lnb = (const float*)d_in[5];
    const float* Wx  = (const float*)d_in[6];
    const float* Wh  = (const float*)d_in[7];
    const float* bg  = (const float*)d_in[8];
    const float* fcW = (const float*)d_in[9];
    const float* fcb = (const float*)d_in[10];
    float* out = (float*)d_out;

    const size_t nTok = (size_t)BB * SS;
    float* hemb = (float*)d_ws;
    float* hout = hemb + nTok * DD;
    unsigned short* Wxh = (unsigned short*)(hout + nTok * DD);
    u64* Xbuf = (u64*)(Wxh + 1048576);
    u64* Rbuf = Xbuf + 4 * 2 * 2048;
    u64* GXbuf = Rbuf + 3 * PRD * 4096;
    unsigned* prog = (unsigned*)(GXbuf + 4 * PGD * 16384);
    int* abortFlag = (int*)(prog + 20);

    const size_t needed = (size_t)((char*)(abortFlag + 1) - (char*)d_ws);
    if (ws_size < needed) return;

    hipMemsetAsync(prog, 0, 20 * sizeof(unsigned) + sizeof(int), stream);

    embed_kernel<<<nTok, DD, 0, stream>>>(x, tf, inW, inb, hemb);
    wxprep_kernel<<<4 * 64, 64, 0, stream>>>(Wx, Wxh);
    mega_kernel<<<80, 256, 0, stream>>>(hemb, Wh, lng, lnb, bg, Wxh, hout,
                                        Xbuf, Rbuf, GXbuf, prog, abortFlag);
    final_kernel<<<BB, 64, 0, stream>>>(hout, fcW, fcb, out);
    (void)in_sizes; (void)n_in; (void)out_size;
}